// Round 1
// baseline (32848.569 us; speedup 1.0000x reference)
//
#include <hip/hip_runtime.h>

// DecoderAttentionRNN on MI355X (gfx950).
// Input dtype (f32 vs bf16 storage) is DETECTED AT RUNTIME (detect_k) and all
// inputs are canonicalized to a bf16 arena in the head of d_out (dead before
// the epilogue GEMM overwrites out). Output dtype follows the detected mode.
//
// Constants: L=2, T=512, B=64, H=512, A=200, E=512, V=10000, S=128, 3H=1536.
//   P1: k_proj via MFMA bf16 GEMM -> kpT[l][t][a][b] bf16 (out-head arena)
//   Step loop: ONE persistent cooperative kernel (step_loop_k) running all
//   128 steps with 5 custom grid barriers per step (replaces 640 launches).
//   EPI: logits via MFMA GEMM (M=8192,N=10000,K=512), B=Pw read natively.

#define DEV __device__ __forceinline__

DEV float bf2f(unsigned short u) {
    unsigned int x = ((unsigned int)u) << 16;
    return __builtin_bit_cast(float, x);
}
DEV unsigned short f2bf(float f) {
    unsigned int x = __builtin_bit_cast(unsigned int, f);
    unsigned int r = (x + 0x7FFFu + ((x >> 16) & 1u)) >> 16;
    return (unsigned short)r;
}
DEV float fin(float v) {  // bit-level finite check (fast-math-proof)
    unsigned int b = __builtin_bit_cast(unsigned int, v);
    return ((b & 0x7F800000u) == 0x7F800000u) ? 1000.0f : v;
}
DEV float rcp_f(float x) { return __builtin_amdgcn_rcpf(x); }
DEV float sigm_f(float x) {
    x = fminf(fmaxf(x, -30.f), 30.f);
    float e = __expf(-x);
    return rcp_f(1.f + e);
}
DEV float tanh_f(float x) {
    x = fminf(fmaxf(x, -15.f), 15.f);
    float ex = __expf(2.f * x);
    return 1.f - 2.f * rcp_f(1.f + ex);
}

typedef __attribute__((ext_vector_type(8))) short short8;   // 8 bf16 (4 VGPRs)
typedef __attribute__((ext_vector_type(4))) float float4v;  // MFMA accumulator

// -------------------------------------------------- detect input storage dtype
__global__ __launch_bounds__(256) void detect_k(const unsigned short* __restrict__ raw,
                                                int* __restrict__ flag) {
    __shared__ int cnt;
    if (threadIdx.x == 0) cnt = 0;
    __syncthreads();
    long idx = 2L * ((long)threadIdx.x * 997 + 13);
    unsigned short u = raw[idx];
    unsigned int e = (u >> 7) & 0xFF;
    if (e >= 0x81) atomicAdd(&cnt, 1);
    __syncthreads();
    if (threadIdx.x == 0) *flag = (cnt >= 40) ? 1 : 0;
}

// -------------------------------------------- canonicalize input -> bf16 arena
__global__ __launch_bounds__(256) void conv_k(const void* __restrict__ src,
                                              unsigned short* __restrict__ dst, long n,
                                              const int* __restrict__ flag) {
    int f = *flag;
    long i0 = (long)blockIdx.x * 256 + threadIdx.x;
    long st = (long)gridDim.x * 256;
    if (f) {
        const float* s = (const float*)src;
        for (long i = i0; i < n; i += st) dst[i] = f2bf(s[i]);
    } else {
        const unsigned short* s = (const unsigned short*)src;
        for (long i = i0; i < n; i += st) dst[i] = s[i];
    }
}

// ---------------------------------------------------------------- P0: init hT
__global__ __launch_bounds__(256) void init_ht_k(const void* __restrict__ ef,
                                                 float* __restrict__ hT,
                                                 const int* __restrict__ flag) {
    int f = *flag;
    int i = blockIdx.x * 256 + threadIdx.x;  // 2*64*512 = 65536
    int l = i >> 15, rem = i & 32767, b = rem >> 9, h = rem & 511;
    float v = f ? ((const float*)ef)[i] : bf2f(((const unsigned short*)ef)[i]);
    hT[(l * 512 + h) * 64 + b] = v;
}

// ------------------------------------------------- MFMA bf16 GEMM (K=512)
__global__ __launch_bounds__(256) void mfma_gemm_k(
    const unsigned short* __restrict__ A, const void* __restrict__ BtV,
    const void* __restrict__ biasV, void* __restrict__ dstV, int Nlim, int mode,
    long Az, long Bz, long biasz, const int* __restrict__ flagp) {
    const int K = 512;
    int f = (mode == 1) ? *flagp : 0;
    int l = blockIdx.z;
    const unsigned short* Ab = A + (long)l * Az;
    const unsigned short* Bb = (const unsigned short*)BtV + (long)l * Bz;
    const float* Bf = (const float*)BtV + (long)l * Bz;
    int tid = threadIdx.x;
    int lane = tid & 63, wid = tid >> 6;
    int wy = wid >> 1, wx = wid & 1;
    int quad = lane >> 4, r16 = lane & 15;
    int m0 = blockIdx.x * 128 + wy * 64;
    int n0 = blockIdx.y * 128 + wx * 64;

    float4v acc[4][4];
    for (int i = 0; i < 4; ++i)
        for (int j = 0; j < 4; ++j) acc[i][j] = (float4v){0.f, 0.f, 0.f, 0.f};

    for (int kt = 0; kt < K / 32; ++kt) {
        int k0 = kt * 32 + quad * 8;
        short8 af[4], bfr[4];
#pragma unroll
        for (int mi = 0; mi < 4; ++mi) {
            int row = m0 + mi * 16 + r16;
            af[mi] = *(const short8*)(Ab + (long)row * K + k0);
        }
#pragma unroll
        for (int ni = 0; ni < 4; ++ni) {
            int col = n0 + ni * 16 + r16;
            if (col < Nlim) {
                if (f) {
                    short8 t;
#pragma unroll
                    for (int j = 0; j < 8; ++j)
                        t[j] = (short)f2bf(Bf[(long)col * K + k0 + j]);
                    bfr[ni] = t;
                } else {
                    bfr[ni] = *(const short8*)(Bb + (long)col * K + k0);
                }
            } else {
                bfr[ni] = (short8){0, 0, 0, 0, 0, 0, 0, 0};
            }
        }
#pragma unroll
        for (int mi = 0; mi < 4; ++mi)
#pragma unroll
            for (int ni = 0; ni < 4; ++ni)
                acc[mi][ni] = __builtin_amdgcn_mfma_f32_16x16x32_bf16(
                    af[mi], bfr[ni], acc[mi][ni], 0, 0, 0);
    }

    unsigned short* dstu = (unsigned short*)dstV;
    float* dstf = (float*)dstV;
    for (int mi = 0; mi < 4; ++mi)
        for (int ni = 0; ni < 4; ++ni) {
            int n = n0 + ni * 16 + r16;
            if (n >= Nlim) continue;
            float bv;
            if (mode == 0)
                bv = bf2f(((const unsigned short*)biasV)[l * biasz + n]);
            else
                bv = f ? ((const float*)biasV)[n] : bf2f(((const unsigned short*)biasV)[n]);
#pragma unroll
            for (int r = 0; r < 4; ++r) {
                int m = m0 + mi * 16 + quad * 4 + r;
                float v = fin(acc[mi][ni][r] + bv);
                if (mode == 0) {
                    int t = m >> 6, b = m & 63;
                    dstu[(((long)(l * 512 + t) * 200 + n) * 64 + b)] = f2bf(v);
                } else {
                    int s = m >> 6, b = m & 63;
                    long oi = ((long)b * 128 + s) * 10000 + n;
                    if (f) dstf[oi] = v;
                    else dstu[oi] = f2bf(v);
                }
            }
        }
}

// ===================== LEGACY per-step kernels (fallback path only) ==========
__global__ __launch_bounds__(256) void q_k(const unsigned short* __restrict__ Qw,
                                           const unsigned short* __restrict__ Qb,
                                           const float* __restrict__ hT,
                                           float* __restrict__ q) {
    __shared__ float red[4][64];
    int blk = blockIdx.x;
    int l = blk / 200, a = blk % 200;
    int tid = threadIdx.x, w = tid >> 6, lane = tid & 63;
    const unsigned short* qr = Qw + (l * 200 + a) * 512;
    const float* hb = hT + l * 512 * 64;
    float acc = 0.f;
    int h0 = w * 128;
    for (int h = h0; h < h0 + 128; h += 8) {
        uint4 u = *(const uint4*)(qr + h);
        const unsigned short* us = (const unsigned short*)&u;
#pragma unroll
        for (int j = 0; j < 8; ++j) acc = fmaf(bf2f(us[j]), hb[(h + j) * 64 + lane], acc);
    }
    red[w][lane] = acc;
    __syncthreads();
    if (w == 0) {
        float v = red[0][lane] + red[1][lane] + red[2][lane] + red[3][lane] +
                  bf2f(Qb[l * 200 + a]);
        q[(l * 200 + a) * 64 + lane] = v;
    }
}

__global__ __launch_bounds__(256) void step1_k(
    const unsigned short* __restrict__ kp, const float* __restrict__ q,
    float* __restrict__ sc, const unsigned short* __restrict__ Vw,
    const unsigned short* __restrict__ Vb, const float* __restrict__ hT,
    const unsigned short* __restrict__ Whh0, const unsigned short* __restrict__ Whh1,
    const unsigned short* __restrict__ bhh0, const unsigned short* __restrict__ bhh1,
    float* __restrict__ gh, const unsigned short* __restrict__ emb,
    const int* __restrict__ tgt, float* __restrict__ xT, int s) {
    int blk = blockIdx.x, tid = threadIdx.x, w = tid >> 6, lane = tid & 63;
    if (blk < 256) {
        int l = blk >> 7, tc = blk & 127, t = tc * 4 + w;
        const unsigned short* kr = kp + (size_t)((l * 512 + t) * 200) * 64;
        const float* qb = q + (l * 200) * 64;
        float acc = 0.f;
#pragma unroll 4
        for (int a = 0; a < 200; ++a) {
            float x = bf2f(kr[a * 64 + lane]) + qb[a * 64 + lane];
            acc = fmaf(bf2f(Vw[l * 200 + a]), tanh_f(x), acc);
        }
        sc[(l * 512 + t) * 64 + lane] = acc + bf2f(Vb[l]);
    } else if (blk < 1024) {
        int widx = (blk - 256) * 4 + w;
        int layer = widx / 1536, j = widx % 1536;
        const unsigned short* Wr = (layer ? Whh1 : Whh0) + (size_t)j * 512;
        const float* hb = hT + layer * 512 * 64;
        float acc = 0.f;
        for (int h = 0; h < 512; h += 8) {
            uint4 u = *(const uint4*)(Wr + h);
            const unsigned short* us = (const unsigned short*)&u;
#pragma unroll
            for (int jj = 0; jj < 8; ++jj)
                acc = fmaf(bf2f(us[jj]), hb[(h + jj) * 64 + lane], acc);
        }
        acc += bf2f((layer ? bhh1 : bhh0)[j]);
        gh[(layer * 1536 + j) * 64 + lane] = acc;
    } else {
        int eb = blk - 1024;
        for (int it = 0; it < 16; ++it) {
            int i = eb * 4096 + it * 256 + tid;
            int b = i >> 9, k = i & 511;
            int tok = (s == 0) ? 0 : tgt[b * 128 + (s - 1)];
            tok = tok < 0 ? 0 : (tok > 9999 ? 9999 : tok);
            float v = bf2f(emb[(size_t)tok * 512 + k]);
            xT[k * 64 + b] = v > 0.f ? v : 0.f;
        }
    }
}

__global__ __launch_bounds__(256) void ctx_k(const float* __restrict__ sc,
                                             const unsigned short* __restrict__ enc,
                                             float* __restrict__ xT) {
    __shared__ float wbuf[1024];
    __shared__ float rbuf[256];
    int blk = blockIdx.x, tid = threadIdx.x;
    int b = blk >> 2, hq = blk & 3;

    float s0[4];
    float lm = -3.0e38f;
#pragma unroll
    for (int i = 0; i < 4; ++i) {
        float v = sc[(tid + i * 256) * 64 + b];
        v = fminf(fmaxf(v, -1.0e30f), 1.0e30f);
        s0[i] = v;
        lm = fmaxf(lm, v);
    }
    rbuf[tid] = lm;
    __syncthreads();
    for (int off = 128; off > 0; off >>= 1) {
        if (tid < off) rbuf[tid] = fmaxf(rbuf[tid], rbuf[tid + off]);
        __syncthreads();
    }
    float M = rbuf[0];
    __syncthreads();
    float ls = 0.f;
#pragma unroll
    for (int i = 0; i < 4; ++i) {
        float e = __expf(fmaxf(s0[i] - M, -80.f));
        wbuf[tid + i * 256] = e;
        ls += e;
    }
    rbuf[tid] = ls;
    __syncthreads();
    for (int off = 128; off > 0; off >>= 1) {
        if (tid < off) rbuf[tid] += rbuf[tid + off];
        __syncthreads();
    }
    float rinv = 1.0f / rbuf[0];

    int h = hq * 128 + (tid & 127), half = tid >> 7;
    float acc = 0.f;
#pragma unroll 8
    for (int lt = half * 512; lt < half * 512 + 512; ++lt)
        acc = fmaf(wbuf[lt], bf2f(enc[((size_t)lt * 64 + b) * 512 + h]), acc);
    __syncthreads();
    rbuf[tid] = acc;
    __syncthreads();
    if (tid < 128)
        xT[(512 + hq * 128 + tid) * 64 + b] = (rbuf[tid] + rbuf[tid + 128]) * rinv;
}

__global__ __launch_bounds__(256) void gru0_k(const float* __restrict__ xT,
                                              const unsigned short* __restrict__ Wih0,
                                              const unsigned short* __restrict__ bih0,
                                              const float* __restrict__ gh,
                                              float* __restrict__ hT) {
    __shared__ float red[4][6][64];
    int blk = blockIdx.x, tid = threadIdx.x, w = tid >> 6, lane = tid & 63;
    int jj0 = blk * 2;
    const unsigned short* r_[6];
    r_[0] = Wih0 + (size_t)(jj0) * 1024;
    r_[1] = Wih0 + (size_t)(jj0 + 1) * 1024;
    r_[2] = Wih0 + (size_t)(jj0 + 512) * 1024;
    r_[3] = Wih0 + (size_t)(jj0 + 513) * 1024;
    r_[4] = Wih0 + (size_t)(jj0 + 1024) * 1024;
    r_[5] = Wih0 + (size_t)(jj0 + 1025) * 1024;
    float acc[6] = {0.f, 0.f, 0.f, 0.f, 0.f, 0.f};
    int k0 = w * 256;
    for (int k = k0; k < k0 + 256; k += 8) {
        uint4 u[6];
#pragma unroll
        for (int i = 0; i < 6; ++i) u[i] = *(const uint4*)(r_[i] + k);
#pragma unroll
        for (int j = 0; j < 8; ++j) {
            float xv = xT[(k + j) * 64 + lane];
#pragma unroll
            for (int i = 0; i < 6; ++i)
                acc[i] = fmaf(bf2f(((const unsigned short*)&u[i])[j]), xv, acc[i]);
        }
    }
#pragma unroll
    for (int i = 0; i < 6; ++i) red[w][i][lane] = acc[i];
    __syncthreads();
    if (w == 0) {
#pragma unroll
        for (int d = 0; d < 2; ++d) {
            int j = jj0 + d;
            float gir = red[0][0 + d][lane] + red[1][0 + d][lane] + red[2][0 + d][lane] +
                        red[3][0 + d][lane] + bf2f(bih0[j]);
            float giz = red[0][2 + d][lane] + red[1][2 + d][lane] + red[2][2 + d][lane] +
                        red[3][2 + d][lane] + bf2f(bih0[512 + j]);
            float gin = red[0][4 + d][lane] + red[1][4 + d][lane] + red[2][4 + d][lane] +
                        red[3][4 + d][lane] + bf2f(bih0[1024 + j]);
            float r = sigm_f(gir + gh[j * 64 + lane]);
            float z = sigm_f(giz + gh[(512 + j) * 64 + lane]);
            float n = tanh_f(gin + r * gh[(1024 + j) * 64 + lane]);
            float hp = hT[j * 64 + lane];
            hT[j * 64 + lane] = (1.f - z) * n + z * hp;
        }
    }
}

__global__ __launch_bounds__(256) void gru1_k(float* __restrict__ hT,
                                              const unsigned short* __restrict__ Wih1,
                                              const unsigned short* __restrict__ bih1,
                                              const float* __restrict__ gh,
                                              unsigned short* __restrict__ h1a, int s) {
    __shared__ float red[4][6][64];
    int blk = blockIdx.x, tid = threadIdx.x, w = tid >> 6, lane = tid & 63;
    int jj0 = blk * 2;
    const float* x = hT;
    float* h1 = hT + 512 * 64;
    const float* gh1 = gh + 1536 * 64;
    const unsigned short* r_[6];
    r_[0] = Wih1 + (size_t)(jj0) * 512;
    r_[1] = Wih1 + (size_t)(jj0 + 1) * 512;
    r_[2] = Wih1 + (size_t)(jj0 + 512) * 512;
    r_[3] = Wih1 + (size_t)(jj0 + 513) * 512;
    r_[4] = Wih1 + (size_t)(jj0 + 1024) * 512;
    r_[5] = Wih1 + (size_t)(jj0 + 1025) * 512;
    float acc[6] = {0.f, 0.f, 0.f, 0.f, 0.f, 0.f};
    int k0 = w * 128;
    for (int k = k0; k < k0 + 128; k += 8) {
        uint4 u[6];
#pragma unroll
        for (int i = 0; i < 6; ++i) u[i] = *(const uint4*)(r_[i] + k);
#pragma unroll
        for (int j = 0; j < 8; ++j) {
            float xv = x[(k + j) * 64 + lane];
#pragma unroll
            for (int i = 0; i < 6; ++i)
                acc[i] = fmaf(bf2f(((const unsigned short*)&u[i])[j]), xv, acc[i]);
        }
    }
#pragma unroll
    for (int i = 0; i < 6; ++i) red[w][i][lane] = acc[i];
    __syncthreads();
    if (w == 0) {
#pragma unroll
        for (int d = 0; d < 2; ++d) {
            int j = jj0 + d;
            float gir = red[0][0 + d][lane] + red[1][0 + d][lane] + red[2][0 + d][lane] +
                        red[3][0 + d][lane] + bf2f(bih1[j]);
            float giz = red[0][2 + d][lane] + red[1][2 + d][lane] + red[2][2 + d][lane] +
                        red[3][2 + d][lane] + bf2f(bih1[512 + j]);
            float gin = red[0][4 + d][lane] + red[1][4 + d][lane] + red[2][4 + d][lane] +
                        red[3][4 + d][lane] + bf2f(bih1[1024 + j]);
            float r = sigm_f(gir + gh1[j * 64 + lane]);
            float z = sigm_f(giz + gh1[(512 + j) * 64 + lane]);
            float n = tanh_f(gin + r * gh1[(1024 + j) * 64 + lane]);
            float hp = h1[j * 64 + lane];
            float hn_ = fin((1.f - z) * n + z * hp);
            h1[j * 64 + lane] = hn_;
            h1a[((size_t)s * 64 + lane) * 512 + j] = f2bf(hn_);
        }
    }
}

// ===================== persistent cooperative step loop ======================
// Custom fast grid barrier: cumulative-count, 16 cacheline-spread arrival
// counters (agent-scope release add), block-0 master sums + release-stores a
// monotone epoch; spinners poll with s_sleep. Bounded spins (guard valves)
// turn any bug into a fast wrong-answer instead of a hang.
// bar layout (u32): [0]=epoch, [32 + i*32] = counter i (i<16), 128B strided.
DEV void gridbar(unsigned* bar, unsigned k) {
    __syncthreads();  // all block stores drained to this XCD's L2
    if (threadIdx.x == 0) {
        // publish my block's writes device-wide (release -> L2 writeback)
        __hip_atomic_fetch_add(bar + 32 + (blockIdx.x & 15) * 32, 1u,
                               __ATOMIC_RELEASE, __HIP_MEMORY_SCOPE_AGENT);
        if (blockIdx.x == 0) {
            unsigned target = gridDim.x * k;
            int guard = 0;
            for (;;) {
                unsigned sum = 0;
#pragma unroll
                for (int i = 0; i < 16; ++i)
                    sum += __hip_atomic_load(bar + 32 + i * 32, __ATOMIC_RELAXED,
                                             __HIP_MEMORY_SCOPE_AGENT);
                if (sum >= target) break;
                if (++guard > (1 << 15)) break;  // safety valve
                __builtin_amdgcn_s_sleep(1);
            }
            __threadfence();  // acquire counters / order before release below
            __hip_atomic_store(bar, k, __ATOMIC_RELEASE, __HIP_MEMORY_SCOPE_AGENT);
        } else {
            int guard = 0;
            while (__hip_atomic_load(bar, __ATOMIC_RELAXED,
                                     __HIP_MEMORY_SCOPE_AGENT) < k) {
                if (++guard > (1 << 16)) break;  // safety valve
                __builtin_amdgcn_s_sleep(2);
            }
            __threadfence();  // invalidate stale L1/L2 before consuming
        }
    }
    __syncthreads();
    __builtin_amdgcn_fence(__ATOMIC_ACQUIRE, "agent");  // all threads: compiler+cache barrier
}

__global__ __launch_bounds__(256, 4) void step_loop_k(
    const unsigned short* __restrict__ kp, const unsigned short* __restrict__ enc,
    const unsigned short* __restrict__ emb, const int* __restrict__ tgt,
    const unsigned short* __restrict__ Qw, const unsigned short* __restrict__ Qb,
    const unsigned short* __restrict__ Vw, const unsigned short* __restrict__ Vb,
    const unsigned short* __restrict__ Whh0, const unsigned short* __restrict__ Whh1,
    const unsigned short* __restrict__ bhh0, const unsigned short* __restrict__ bhh1,
    const unsigned short* __restrict__ Wih0, const unsigned short* __restrict__ bih0,
    const unsigned short* __restrict__ Wih1, const unsigned short* __restrict__ bih1,
    float* hT, float* q, float* sc, float* xT, float* gh,
    unsigned short* h1a, unsigned* bar) {
    int tid = threadIdx.x, w = tid >> 6, lane = tid & 63;
    __shared__ float smem[1536];
    unsigned bk = 0;

    for (int s = 0; s < 128; ++s) {
        // ---------------- Phase A: q (400) + gh (768) + emb (8) = 1176 units
        for (unsigned u = blockIdx.x; u < 1176; u += gridDim.x) {
            if (u < 400) {
                int l = (int)u / 200, a = (int)u % 200;
                const unsigned short* qr = Qw + (l * 200 + a) * 512;
                const float* hb = hT + l * 512 * 64;
                float acc = 0.f;
                int h0 = w * 128;
                for (int h = h0; h < h0 + 128; h += 8) {
                    uint4 uu = *(const uint4*)(qr + h);
                    const unsigned short* us = (const unsigned short*)&uu;
#pragma unroll
                    for (int j = 0; j < 8; ++j)
                        acc = fmaf(bf2f(us[j]), hb[(h + j) * 64 + lane], acc);
                }
                float(*red)[64] = (float(*)[64])smem;
                red[w][lane] = acc;
                __syncthreads();
                if (w == 0)
                    q[(l * 200 + a) * 64 + lane] = red[0][lane] + red[1][lane] +
                                                   red[2][lane] + red[3][lane] +
                                                   bf2f(Qb[l * 200 + a]);
            } else if (u < 1168) {
                int widx = ((int)u - 400) * 4 + w;
                int layer = widx / 1536, j = widx - layer * 1536;
                const unsigned short* Wr = (layer ? Whh1 : Whh0) + (size_t)j * 512;
                const float* hb = hT + layer * 512 * 64;
                float acc = 0.f;
                for (int h = 0; h < 512; h += 8) {
                    uint4 uu = *(const uint4*)(Wr + h);
                    const unsigned short* us = (const unsigned short*)&uu;
#pragma unroll
                    for (int jj = 0; jj < 8; ++jj)
                        acc = fmaf(bf2f(us[jj]), hb[(h + jj) * 64 + lane], acc);
                }
                acc += bf2f((layer ? bhh1 : bhh0)[j]);
                gh[(layer * 1536 + j) * 64 + lane] = acc;
            } else {
                int eb = (int)u - 1168;
                for (int it = 0; it < 16; ++it) {
                    int i = eb * 4096 + it * 256 + tid;
                    int b = i >> 9, k = i & 511;
                    int tok = (s == 0) ? 0 : tgt[b * 128 + (s - 1)];
                    tok = tok < 0 ? 0 : (tok > 9999 ? 9999 : tok);
                    float v = bf2f(emb[(size_t)tok * 512 + k]);
                    xT[k * 64 + b] = v > 0.f ? v : 0.f;
                }
            }
            __syncthreads();
        }
        gridbar(bar, ++bk);

        // ---------------- Phase B: scores, 1024 units (a-dim split 4 waves)
        for (unsigned u = blockIdx.x; u < 1024; u += gridDim.x) {
            int l = (int)(u >> 9), t = (int)(u & 511);
            const unsigned short* kr = kp + (size_t)((l * 512 + t) * 200) * 64;
            const float* qb = q + (l * 200) * 64;
            float acc = 0.f;
            int a0 = w * 50;
#pragma unroll 2
            for (int a = a0; a < a0 + 50; ++a) {
                float x = bf2f(kr[a * 64 + lane]) + qb[a * 64 + lane];
                acc = fmaf(bf2f(Vw[l * 200 + a]), tanh_f(x), acc);
            }
            float(*red)[64] = (float(*)[64])smem;
            red[w][lane] = acc;
            __syncthreads();
            if (w == 0)
                sc[(l * 512 + t) * 64 + lane] = red[0][lane] + red[1][lane] +
                                                red[2][lane] + red[3][lane] +
                                                bf2f(Vb[l]);
            __syncthreads();
        }
        gridbar(bar, ++bk);

        // ---------------- Phase C: softmax + context, 256 units
        for (unsigned u = blockIdx.x; u < 256; u += gridDim.x) {
            int b = (int)(u >> 2), hq = (int)(u & 3);
            float* wbuf = smem;         // 1024
            float* rbuf = smem + 1024;  // 256
            float s0[4];
            float lm = -3.0e38f;
#pragma unroll
            for (int i = 0; i < 4; ++i) {
                float v = sc[(tid + i * 256) * 64 + b];
                v = fminf(fmaxf(v, -1.0e30f), 1.0e30f);
                s0[i] = v;
                lm = fmaxf(lm, v);
            }
            rbuf[tid] = lm;
            __syncthreads();
            for (int off = 128; off > 0; off >>= 1) {
                if (tid < off) rbuf[tid] = fmaxf(rbuf[tid], rbuf[tid + off]);
                __syncthreads();
            }
            float M = rbuf[0];
            __syncthreads();
            float ls = 0.f;
#pragma unroll
            for (int i = 0; i < 4; ++i) {
                float e = __expf(fmaxf(s0[i] - M, -80.f));
                wbuf[tid + i * 256] = e;
                ls += e;
            }
            rbuf[tid] = ls;
            __syncthreads();
            for (int off = 128; off > 0; off >>= 1) {
                if (tid < off) rbuf[tid] += rbuf[tid + off];
                __syncthreads();
            }
            float rinv = 1.0f / rbuf[0];

            int h = hq * 128 + (tid & 127), half = tid >> 7;
            float acc = 0.f;
#pragma unroll 8
            for (int lt = half * 512; lt < half * 512 + 512; ++lt)
                acc = fmaf(wbuf[lt], bf2f(enc[((size_t)lt * 64 + b) * 512 + h]), acc);
            __syncthreads();
            rbuf[tid] = acc;
            __syncthreads();
            if (tid < 128)
                xT[(512 + hq * 128 + tid) * 64 + b] = (rbuf[tid] + rbuf[tid + 128]) * rinv;
            __syncthreads();
        }
        gridbar(bar, ++bk);

        // ---------------- Phase D: GRU layer 0, 512 units (k split 4 waves)
        for (unsigned u = blockIdx.x; u < 512; u += gridDim.x) {
            int j = (int)u;
            const unsigned short* r0 = Wih0 + (size_t)j * 1024;
            const unsigned short* r1 = Wih0 + (size_t)(512 + j) * 1024;
            const unsigned short* r2 = Wih0 + (size_t)(1024 + j) * 1024;
            float a0 = 0.f, a1 = 0.f, a2 = 0.f;
            int k0 = w * 256;
            for (int k = k0; k < k0 + 256; k += 8) {
                uint4 u0 = *(const uint4*)(r0 + k);
                uint4 u1 = *(const uint4*)(r1 + k);
                uint4 u2 = *(const uint4*)(r2 + k);
#pragma unroll
                for (int jj = 0; jj < 8; ++jj) {
                    float xv = xT[(k + jj) * 64 + lane];
                    a0 = fmaf(bf2f(((const unsigned short*)&u0)[jj]), xv, a0);
                    a1 = fmaf(bf2f(((const unsigned short*)&u1)[jj]), xv, a1);
                    a2 = fmaf(bf2f(((const unsigned short*)&u2)[jj]), xv, a2);
                }
            }
            float(*red)[3][64] = (float(*)[3][64])smem;
            red[w][0][lane] = a0;
            red[w][1][lane] = a1;
            red[w][2][lane] = a2;
            __syncthreads();
            if (w == 0) {
                float gir = red[0][0][lane] + red[1][0][lane] + red[2][0][lane] +
                            red[3][0][lane] + bf2f(bih0[j]);
                float giz = red[0][1][lane] + red[1][1][lane] + red[2][1][lane] +
                            red[3][1][lane] + bf2f(bih0[512 + j]);
                float gin = red[0][2][lane] + red[1][2][lane] + red[2][2][lane] +
                            red[3][2][lane] + bf2f(bih0[1024 + j]);
                float r = sigm_f(gir + gh[j * 64 + lane]);
                float z = sigm_f(giz + gh[(512 + j) * 64 + lane]);
                float n = tanh_f(gin + r * gh[(1024 + j) * 64 + lane]);
                float hp = hT[j * 64 + lane];
                hT[j * 64 + lane] = (1.f - z) * n + z * hp;
            }
            __syncthreads();
        }
        gridbar(bar, ++bk);

        // ---------------- Phase E: GRU layer 1 + h1 history, 512 units
        for (unsigned u = blockIdx.x; u < 512; u += gridDim.x) {
            int j = (int)u;
            const float* x = hT;  // h0 (new)
            float* h1 = hT + 512 * 64;
            const float* gh1 = gh + 1536 * 64;
            const unsigned short* r0 = Wih1 + (size_t)j * 512;
            const unsigned short* r1 = Wih1 + (size_t)(512 + j) * 512;
            const unsigned short* r2 = Wih1 + (size_t)(1024 + j) * 512;
            float a0 = 0.f, a1 = 0.f, a2 = 0.f;
            int k0 = w * 128;
            for (int k = k0; k < k0 + 128; k += 8) {
                uint4 u0 = *(const uint4*)(r0 + k);
                uint4 u1 = *(const uint4*)(r1 + k);
                uint4 u2 = *(const uint4*)(r2 + k);
#pragma unroll
                for (int jj = 0; jj < 8; ++jj) {
                    float xv = x[(k + jj) * 64 + lane];
                    a0 = fmaf(bf2f(((const unsigned short*)&u0)[jj]), xv, a0);
                    a1 = fmaf(bf2f(((const unsigned short*)&u1)[jj]), xv, a1);
                    a2 = fmaf(bf2f(((const unsigned short*)&u2)[jj]), xv, a2);
                }
            }
            float(*red)[3][64] = (float(*)[3][64])smem;
            red[w][0][lane] = a0;
            red[w][1][lane] = a1;
            red[w][2][lane] = a2;
            __syncthreads();
            if (w == 0) {
                float gir = red[0][0][lane] + red[1][0][lane] + red[2][0][lane] +
                            red[3][0][lane] + bf2f(bih1[j]);
                float giz = red[0][1][lane] + red[1][1][lane] + red[2][1][lane] +
                            red[3][1][lane] + bf2f(bih1[512 + j]);
                float gin = red[0][2][lane] + red[1][2][lane] + red[2][2][lane] +
                            red[3][2][lane] + bf2f(bih1[1024 + j]);
                float r = sigm_f(gir + gh1[j * 64 + lane]);
                float z = sigm_f(giz + gh1[(512 + j) * 64 + lane]);
                float n = tanh_f(gin + r * gh1[(1024 + j) * 64 + lane]);
                float hp = h1[j * 64 + lane];
                float hn_ = fin((1.f - z) * n + z * hp);
                h1[j * 64 + lane] = hn_;
                h1a[((size_t)s * 64 + lane) * 512 + j] = f2bf(hn_);
            }
            __syncthreads();
        }
        gridbar(bar, ++bk);
    }
}

// ----------------------------------------------------------------- launcher
extern "C" void kernel_launch(void* const* d_in, const int* in_sizes, int n_in,
                              void* d_out, int out_size, void* d_ws, size_t ws_size,
                              hipStream_t stream) {
    const void* enc = d_in[0];
    const void* efin = d_in[1];
    const int* tgt = (const int*)d_in[2];
    const void* Qw = d_in[3];
    const void* Qb = d_in[4];
    const void* Kw = d_in[5];
    const void* Kb = d_in[6];
    const void* Vw = d_in[7];
    const void* Vb = d_in[8];
    const void* emb = d_in[9];
    const void* Wih0 = d_in[10];
    const void* Whh0 = d_in[11];
    const void* bih0 = d_in[12];
    const void* bhh0 = d_in[13];
    const void* Wih1 = d_in[14];
    const void* Whh1 = d_in[15];
    const void* bih1 = d_in[16];
    const void* bhh1 = d_in[17];
    const void* Pw = d_in[18];
    const void* Pb = d_in[19];

    // --- bf16 arena in out head (u16 elements); all dead before epilogue GEMM.
    unsigned short* outa = (unsigned short*)d_out;
    unsigned short* kp = outa + 0L;              // 13,107,200  [2][512][200][64]
    unsigned short* enc_c = outa + 13107200L;    // 33,554,432
    unsigned short* emb_c = outa + 46661632L;    //  5,120,000
    unsigned short* Qw_c = outa + 51781632L;     //    204,800
    unsigned short* Kw_c = outa + 51986432L;     //    204,800
    unsigned short* Wih0_c = outa + 52191232L;   //  1,572,864
    unsigned short* Whh0_c = outa + 53764096L;   //    786,432
    unsigned short* Wih1_c = outa + 54550528L;   //    786,432
    unsigned short* Whh1_c = outa + 55336960L;   //    786,432
    unsigned short* sm = outa + 56123392L;       //      7,376 small tensors
    unsigned short* Qb_c = sm + 0;
    unsigned short* Kb_c = sm + 408;
    unsigned short* Vw_c = sm + 816;
    unsigned short* Vb_c = sm + 1224;
    unsigned short* bih0_c = sm + 1232;
    unsigned short* bhh0_c = sm + 2768;
    unsigned short* bih1_c = sm + 4304;
    unsigned short* bhh1_c = sm + 5840;
    // barrier state: u16 offset 57,000,000 (byte 114,000,000; 128B aligned).
    // Beyond arena end (56.13M u16), within out in BOTH dtype worlds
    // (bf16-world out = 81.92M u16), and overwritten by the epilogue GEMM.
    unsigned* bar = (unsigned*)(outa + 57000000L);  // [0]=epoch, +32.. counters

    // --- workspace (10.07 MB): flag + f32 state + h1 history
    char* w = (char*)d_ws;
    int* flag = (int*)w;                       w += 256;
    float* hT = (float*)w;                     w += 262144;   // [2][512][64]
    float* q = (float*)w;                      w += 102400;   // [2][200][64]
    float* sc = (float*)w;                     w += 262144;   // [1024][64]
    float* xT = (float*)w;                     w += 262144;   // [1024][64]
    float* gh = (float*)w;                     w += 786432;   // [2][1536][64]
    unsigned short* h1a = (unsigned short*)w;  w += 8388608;  // [128][64][512]

    detect_k<<<1, 256, 0, stream>>>((const unsigned short*)emb, flag);
    hipMemsetAsync(bar, 0, (32 + 16 * 32) * sizeof(unsigned), stream);

    conv_k<<<2048, 256, 0, stream>>>(enc, enc_c, 33554432L, flag);
    conv_k<<<1024, 256, 0, stream>>>(emb, emb_c, 5120000L, flag);
    conv_k<<<256, 256, 0, stream>>>(Qw, Qw_c, 204800L, flag);
    conv_k<<<256, 256, 0, stream>>>(Kw, Kw_c, 204800L, flag);
    conv_k<<<512, 256, 0, stream>>>(Wih0, Wih0_c, 1572864L, flag);
    conv_k<<<256, 256, 0, stream>>>(Whh0, Whh0_c, 786432L, flag);
    conv_k<<<256, 256, 0, stream>>>(Wih1, Wih1_c, 786432L, flag);
    conv_k<<<256, 256, 0, stream>>>(Whh1, Whh1_c, 786432L, flag);
    conv_k<<<2, 256, 0, stream>>>(Qb, Qb_c, 400L, flag);
    conv_k<<<2, 256, 0, stream>>>(Kb, Kb_c, 400L, flag);
    conv_k<<<2, 256, 0, stream>>>(Vw, Vw_c, 400L, flag);
    conv_k<<<1, 256, 0, stream>>>(Vb, Vb_c, 2L, flag);
    conv_k<<<6, 256, 0, stream>>>(bih0, bih0_c, 1536L, flag);
    conv_k<<<6, 256, 0, stream>>>(bhh0, bhh0_c, 1536L, flag);
    conv_k<<<6, 256, 0, stream>>>(bih1, bih1_c, 1536L, flag);
    conv_k<<<6, 256, 0, stream>>>(bhh1, bhh1_c, 1536L, flag);

    init_ht_k<<<256, 256, 0, stream>>>(efin, hT, flag);

    // k_proj: A=enc_c, B=Kw_c, bias=Kb_c (all canonical bf16)
    mfma_gemm_k<<<dim3(256, 2, 2), 256, 0, stream>>>(
        enc_c, Kw_c, Kb_c, kp, 200, 0, (long)32768 * 512, (long)200 * 512, 200, flag);

    // ---- persistent cooperative step loop (all 128 steps, 5 barriers/step)
    int maxb = 0;
    if (hipOccupancyMaxActiveBlocksPerMultiprocessor(&maxb, (const void*)step_loop_k,
                                                     256, 0) != hipSuccess ||
        maxb <= 0)
        maxb = 2;
    long nbl = (long)maxb * 256;
    int nb = (int)(nbl > 1024 ? 1024 : nbl);

    const unsigned short* p_kp = kp;
    const unsigned short* p_enc = enc_c;
    const unsigned short* p_emb = emb_c;
    const int* p_tgt = tgt;
    const unsigned short* p_Qw = Qw_c;
    const unsigned short* p_Qb = Qb_c;
    const unsigned short* p_Vw = Vw_c;
    const unsigned short* p_Vb = Vb_c;
    const unsigned short* p_Whh0 = Whh0_c;
    const unsigned short* p_Whh1 = Whh1_c;
    const unsigned short* p_bhh0 = bhh0_c;
    const unsigned short* p_bhh1 = bhh1_c;
    const unsigned short* p_Wih0 = Wih0_c;
    const unsigned short* p_bih0 = bih0_c;
    const unsigned short* p_Wih1 = Wih1_c;
    const unsigned short* p_bih1 = bih1_c;
    float* p_hT = hT;
    float* p_q = q;
    float* p_sc = sc;
    float* p_xT = xT;
    float* p_gh = gh;
    unsigned short* p_h1a = h1a;
    unsigned* p_bar = bar;
    void* cargs[] = {&p_kp,   &p_enc,  &p_emb,  &p_tgt,  &p_Qw,   &p_Qb,
                     &p_Vw,   &p_Vb,   &p_Whh0, &p_Whh1, &p_bhh0, &p_bhh1,
                     &p_Wih0, &p_bih0, &p_Wih1, &p_bih1, &p_hT,   &p_q,
                     &p_sc,   &p_xT,   &p_gh,   &p_h1a,  &p_bar};
    hipError_t ce = hipLaunchCooperativeKernel((const void*)step_loop_k, dim3(nb),
                                               dim3(256), cargs, 0, stream);
    if (ce != hipSuccess) {
        // fallback: legacy 5-kernel-per-step loop (previous verified path)
        for (int s = 0; s < 128; ++s) {
            q_k<<<400, 256, 0, stream>>>(Qw_c, Qb_c, hT, q);
            step1_k<<<1032, 256, 0, stream>>>(kp, q, sc, Vw_c, Vb_c, hT, Whh0_c,
                                              Whh1_c, bhh0_c, bhh1_c, gh, emb_c, tgt,
                                              xT, s);
            ctx_k<<<256, 256, 0, stream>>>(sc, enc_c, xT);
            gru0_k<<<256, 256, 0, stream>>>(xT, Wih0_c, bih0_c, gh, hT);
            gru1_k<<<256, 256, 0, stream>>>(hT, Wih1_c, bih1_c, gh, h1a, s);
        }
    }

    // logits: A=h1a (bf16, ws), B=Pw native (flag-branched), bias=Pb native
    mfma_gemm_k<<<dim3(64, 79, 1), 256, 0, stream>>>(h1a, Pw, Pb, d_out, 10000, 1, 0,
                                                     0, 0, flag);
}